// Round 2
// baseline (506.663 us; speedup 1.0000x reference)
//
#include <hip/hip_runtime.h>
#include <stdint.h>

#define ROWLEN 8192
#define KSEL 64
#define NT 256
#define VPT 8      // float4 per thread -> 32 elements per thread
#define NH 8       // round-1 histogram copies (wave * lane-parity)
#define HPAD 264   // 256 bins + 8 skew so copies land on different banks
#define CAP 512    // candidate-list capacity per tail (fallback guard)
#define MAXEQ 256  // tie-resolution capacity (matches original semantics)

// Order-preserving f32 -> u32 key: larger float <=> larger key (total order).
__device__ __forceinline__ uint32_t f2key(float f) {
    uint32_t u = __float_as_uint(f);
    return (u & 0x80000000u) ? ~u : (u | 0x80000000u);
}
// inverse of f2key
__device__ __forceinline__ float key2f(uint32_t k) {
    uint32_t u = (k & 0x80000000u) ? (k ^ 0x80000000u) : ~k;
    return __uint_as_float(u);
}

struct Sel2 { uint32_t bin0, k0, cnt0, bin1, k1, cnt1; };

// Packed dual selection: both tails' 256-bin histograms are scanned in ONE
// block-scan. Counts and their prefix sums are <= 8192 < 2^16, so packing
// (c0 | c1<<16) cannot carry between halves. Thread t owns bin t (ascending
// in transformed-key space). Finds, per half, the bin holding the kX-th
// largest (descending bin order) given total SX.
__device__ __forceinline__ Sel2 select2(uint32_t c0, uint32_t c1,
                                        uint32_t S0, uint32_t k0,
                                        uint32_t S1, uint32_t k1,
                                        uint32_t* wsum, uint32_t* bc,
                                        int tid, int lane, int wid) {
    uint32_t p = c0 | (c1 << 16);           // packed wave-inclusive scan
    #pragma unroll
    for (int d = 1; d < 64; d <<= 1) {
        uint32_t y = __shfl_up(p, (unsigned)d, 64);
        if (lane >= d) p += y;
    }
    if (lane == 63) wsum[wid] = p;
    __syncthreads();
    uint32_t off = 0;
    #pragma unroll
    for (int w = 0; w < 4; ++w) if (w < wid) off += wsum[w];
    p += off;                               // packed block-inclusive prefix
    uint32_t p0 = p & 0xFFFFu, p1 = p >> 16;
    uint32_t t0 = S0 - k0 + 1u;             // ascending-prefix crossing
    uint32_t t1 = S1 - k1 + 1u;
    if (p0 >= t0 && (p0 - c0) < t0) {       // unique thread per half (c>=1)
        bc[0] = (uint32_t)tid; bc[1] = k0 - (S0 - p0); bc[2] = c0;
    }
    if (p1 >= t1 && (p1 - c1) < t1) {
        bc[3] = (uint32_t)tid; bc[4] = k1 - (S1 - p1); bc[5] = c1;
    }
    __syncthreads();
    Sel2 o;
    o.bin0 = bc[0]; o.k0 = bc[1]; o.cnt0 = bc[2];
    o.bin1 = bc[3]; o.k1 = bc[4]; o.cnt1 = bc[5];
    return o;
}

extern "C" __global__ void __launch_bounds__(NT, 4)
topk_mask_kernel(const float* __restrict__ x, const float* __restrict__ w,
                 float* __restrict__ out) {
    __shared__ uint32_t hist8[NH][HPAD];    // 8448 B, round-1 only
    __shared__ uint32_t hist2[2][256];      // rounds 2-4, both passes at once
    __shared__ uint32_t wsum[4];
    __shared__ uint32_t bc[6];
    __shared__ uint32_t eqidx[2][MAXEQ];    // threshold-equal indices per pass
    __shared__ uint32_t s_ec2[2];
    __shared__ int s_cut2[2];
    __shared__ uint32_t listKey[2][CAP];    // compacted candidates (transformed)
    __shared__ uint16_t listIdx[2][CAP];
    __shared__ uint32_t listCnt[2];

    const int tid  = threadIdx.x;
    const int lane = tid & 63;
    const int wid  = tid >> 6;
    const int hcopy = (wid << 1) | (lane & 1);
    const size_t row = blockIdx.x;

    const float4* xr = (const float4*)(x + row * (size_t)ROWLEN);
    const float4* wr = (const float4*)w;

    // ---- load row (coalesced 16B/lane), form products, keep KEYS in regs ----
    uint32_t key[VPT][4];
    #pragma unroll
    for (int j = 0; j < VPT; ++j) {
        float4 a = xr[j * NT + tid];
        float4 b = wr[j * NT + tid];
        key[j][0] = f2key(a.x * b.x);
        key[j][1] = f2key(a.y * b.y);
        key[j][2] = f2key(a.z * b.z);
        key[j][3] = f2key(a.w * b.w);
    }

    // ---- single fused zero-init phase ----
    for (int i = tid; i < NH * HPAD; i += NT) ((uint32_t*)hist8)[i] = 0;
    hist2[0][tid] = 0; hist2[1][tid] = 0;
    if (tid < 2) { listCnt[tid] = 0; s_ec2[tid] = 0; s_cut2[tid] = 0x7FFFFFFF; }
    __syncthreads();

    // ---- round-1 histogram over top byte (8 skewed copies) ----
    #pragma unroll
    for (int j = 0; j < VPT; ++j)
        #pragma unroll
        for (int c = 0; c < 4; ++c)
            atomicAdd(&hist8[hcopy][key[j][c] >> 24], 1u);
    __syncthreads();

    // ---- packed round-1 selection for BOTH tails ----
    // transformed top byte of ~key is 255 - top byte of key (no borrow from
    // the low 24 bits can reach the top byte).
    uint32_t c0 = 0, c1 = 0;
    #pragma unroll
    for (int h = 0; h < NH; ++h) {
        c0 += hist8[h][tid];
        c1 += hist8[h][255 - tid];
    }
    Sel2 s1 = select2(c0, c1, ROWLEN, KSEL, ROWLEN, KSEL, wsum, bc, tid, lane, wid);
    uint32_t pref0 = s1.bin0 << 24, k0 = s1.k0, S0 = s1.cnt0;
    uint32_t pref1 = s1.bin1 << 24, k1 = s1.k1, S1 = s1.cnt1;
    const bool ul0 = S0 <= CAP;
    const bool ul1 = S1 <= CAP;
    const uint32_t bRawHi = s1.bin0;          // raw key>>24 of hi bin
    const uint32_t bRawLo = 255u - s1.bin1;   // raw key>>24 of lo bin

    // ---- compact bin-matching candidates, both tails, ONE register scan ----
    // Wave-ballot aggregation: one LDS atomic per wave per match-group
    // instead of one contended atomic per matching element. List order is
    // irrelevant (ties are resolved by element index, not list position).
    if (ul0 || ul1) {
        #pragma unroll
        for (int j = 0; j < VPT; ++j)
            #pragma unroll
            for (int c = 0; c < 4; ++c) {
                uint32_t kk = key[j][c];
                uint32_t b = kk >> 24;
                bool m0 = ul0 && (b == bRawHi);
                bool m1 = ul1 && (b == bRawLo);
                unsigned long long B0 = __ballot(m0);
                unsigned long long B1 = __ballot(m1);
                uint32_t idx = (uint32_t)((j * NT + tid) * 4 + c);
                if (B0) {
                    uint32_t base = 0;
                    if (lane == 0) base = atomicAdd(&listCnt[0], (uint32_t)__popcll(B0));
                    base = __shfl(base, 0, 64);
                    if (m0) {
                        uint32_t pos = base + (uint32_t)__popcll(B0 & ((1ull << lane) - 1ull));
                        listKey[0][pos] = kk;              // exactly cnt<=CAP match
                        listIdx[0][pos] = (uint16_t)idx;
                    }
                }
                if (B1) {
                    uint32_t base = 0;
                    if (lane == 0) base = atomicAdd(&listCnt[1], (uint32_t)__popcll(B1));
                    base = __shfl(base, 0, 64);
                    if (m1) {
                        uint32_t pos = base + (uint32_t)__popcll(B1 & ((1ull << lane) - 1ull));
                        listKey[1][pos] = ~kk;             // store transformed key
                        listIdx[1][pos] = (uint16_t)idx;
                    }
                }
            }
    }
    __syncthreads();
    const uint32_t lc0 = listCnt[0], lc1 = listCnt[1];

    // ---- rounds 2..4, BOTH passes refined simultaneously ----
    for (int shift = 16; shift >= 0; shift -= 8) {
        if (ul0) {
            for (uint32_t i = (uint32_t)tid; i < lc0; i += NT) {
                uint32_t tk = listKey[0][i];
                if (((tk ^ pref0) >> (shift + 8)) == 0u)
                    atomicAdd(&hist2[0][(tk >> shift) & 0xFFu], 1u);
            }
        } else {
            #pragma unroll
            for (int j = 0; j < VPT; ++j)
                #pragma unroll
                for (int c = 0; c < 4; ++c) {
                    uint32_t tk = key[j][c];
                    if (((tk ^ pref0) >> (shift + 8)) == 0u)
                        atomicAdd(&hist2[0][(tk >> shift) & 0xFFu], 1u);
                }
        }
        if (ul1) {
            for (uint32_t i = (uint32_t)tid; i < lc1; i += NT) {
                uint32_t tk = listKey[1][i];
                if (((tk ^ pref1) >> (shift + 8)) == 0u)
                    atomicAdd(&hist2[1][(tk >> shift) & 0xFFu], 1u);
            }
        } else {
            #pragma unroll
            for (int j = 0; j < VPT; ++j)
                #pragma unroll
                for (int c = 0; c < 4; ++c) {
                    uint32_t tk = ~key[j][c];
                    if (((tk ^ pref1) >> (shift + 8)) == 0u)
                        atomicAdd(&hist2[1][(tk >> shift) & 0xFFu], 1u);
                }
        }
        __syncthreads();
        uint32_t r0 = hist2[0][tid], r1 = hist2[1][tid];
        hist2[0][tid] = 0; hist2[1][tid] = 0;   // own-slot zero for next round;
                                                 // ordered by select2's barriers
        Sel2 s = select2(r0, r1, S0, k0, S1, k1, wsum, bc, tid, lane, wid);
        pref0 |= s.bin0 << shift; k0 = s.k0; S0 = s.cnt0;
        pref1 |= s.bin1 << shift; k1 = s.k1; S1 = s.cnt1;
    }

    // ---- UNCONDITIONAL tie resolution, both passes in one phase ----
    // Collect indices whose transformed key == prefix; cut = index of the
    // kcur-th lowest index among them. kcur == S => all equals zeroed.
    if (ul0) {
        for (uint32_t i = (uint32_t)tid; i < lc0; i += NT)
            if (listKey[0][i] == pref0) {
                uint32_t pos = atomicAdd(&s_ec2[0], 1u);
                if (pos < MAXEQ) eqidx[0][pos] = listIdx[0][i];
            }
    } else {
        #pragma unroll
        for (int j = 0; j < VPT; ++j)
            #pragma unroll
            for (int c = 0; c < 4; ++c)
                if (key[j][c] == pref0) {
                    uint32_t pos = atomicAdd(&s_ec2[0], 1u);
                    if (pos < MAXEQ) eqidx[0][pos] = (uint32_t)((j * NT + tid) * 4 + c);
                }
    }
    if (ul1) {
        for (uint32_t i = (uint32_t)tid; i < lc1; i += NT)
            if (listKey[1][i] == pref1) {
                uint32_t pos = atomicAdd(&s_ec2[1], 1u);
                if (pos < MAXEQ) eqidx[1][pos] = listIdx[1][i];
            }
    } else {
        #pragma unroll
        for (int j = 0; j < VPT; ++j)
            #pragma unroll
            for (int c = 0; c < 4; ++c)
                if (~key[j][c] == pref1) {
                    uint32_t pos = atomicAdd(&s_ec2[1], 1u);
                    if (pos < MAXEQ) eqidx[1][pos] = (uint32_t)((j * NT + tid) * 4 + c);
                }
    }
    __syncthreads();
    const uint32_t ec0 = s_ec2[0], ec1 = s_ec2[1];
    if (ec0 <= MAXEQ)
        for (uint32_t i = (uint32_t)tid; i < ec0; i += NT) {
            uint32_t my = eqidx[0][i], rank = 0;
            for (uint32_t j2 = 0; j2 < ec0; ++j2)
                rank += (eqidx[0][j2] < my) ? 1u : 0u;
            if (rank + 1u == k0) s_cut2[0] = (int)my;      // unique writer
        }
    if (ec1 <= MAXEQ)
        for (uint32_t i = (uint32_t)tid; i < ec1; i += NT) {
            uint32_t my = eqidx[1][i], rank = 0;
            for (uint32_t j2 = 0; j2 < ec1; ++j2)
                rank += (eqidx[1][j2] < my) ? 1u : 0u;
            if (rank + 1u == k1) s_cut2[1] = (int)my;      // unique writer
        }
    __syncthreads();

    const uint32_t Thi = pref0, Tlo = pref1;
    const int cutHi = (ec0 <= MAXEQ) ? s_cut2[0] : 0x7FFFFFFF;
    const int cutLo = (ec1 <= MAXEQ) ? s_cut2[1] : 0x7FFFFFFF;

    // ---- masked output (coalesced 16B/lane regular stores) ----
    // nt stores measured +49MB write amplification on gfx950 -> reverted.
    float4* orow = (float4*)(out + row * (size_t)ROWLEN);
    #pragma unroll
    for (int j = 0; j < VPT; ++j) {
        float f[4];
        #pragma unroll
        for (int c = 0; c < 4; ++c) {
            uint32_t kh = key[j][c];
            uint32_t kl = ~kh;
            int idx = (j * NT + tid) * 4 + c;
            bool z = (kh > Thi) || (kh == Thi && idx <= cutHi) ||
                     (kl > Tlo) || (kl == Tlo && idx <= cutLo);
            f[c] = z ? 0.0f : key2f(kh);
        }
        orow[j * NT + tid] = make_float4(f[0], f[1], f[2], f[3]);
    }
}

extern "C" void kernel_launch(void* const* d_in, const int* in_sizes, int n_in,
                              void* d_out, int out_size, void* d_ws, size_t ws_size,
                              hipStream_t stream) {
    const float* x = (const float*)d_in[0];
    const float* w = (const float*)d_in[1];
    // d_in[2] is k (scalar int) == 64, baked in as KSEL
    float* out = (float*)d_out;
    const int rows = out_size / ROWLEN;   // 8192
    topk_mask_kernel<<<dim3(rows), dim3(NT), 0, stream>>>(x, w, out);
}

// Round 3
// 474.268 us; speedup vs baseline: 1.0683x; 1.0683x over previous
//
#include <hip/hip_runtime.h>
#include <stdint.h>

#define ROWLEN 8192
#define KSEL 64
#define NT 256
#define VPT 8      // float4 per thread -> 32 elements per thread
#define NH 8       // round-1 histogram copies (wave * lane-parity)
#define HPAD 264   // 256 bins + 8 skew so copies land on different banks
#define CAP 512    // candidate-list capacity per tail (fallback guard)
#define MAXEQ 256  // tie-resolution capacity (matches original semantics)
#define HXS 320    // skewed per-wave 256-bin hist allocation
#define HX(b) ((b) + ((b) >> 2))   // stride-5 skew: max 2-way bank aliasing

// Order-preserving f32 -> u32 key: larger float <=> larger key (total order).
__device__ __forceinline__ uint32_t f2key(float f) {
    uint32_t u = __float_as_uint(f);
    return (u & 0x80000000u) ? ~u : (u | 0x80000000u);
}
// inverse of f2key
__device__ __forceinline__ float key2f(uint32_t k) {
    uint32_t u = (k & 0x80000000u) ? (k ^ 0x80000000u) : ~k;
    return __uint_as_float(u);
}

struct SelOut { uint32_t bin, k, cnt; };

// Block-wide 256-bin select (FALLBACK PATH ONLY). Thread t owns bin t
// (ascending). Finds bin holding the kcur-th largest (descending bin order).
__device__ __forceinline__ SelOut select256(uint32_t cnt, uint32_t S, uint32_t kcur,
                                            uint32_t* wsum, uint32_t* bc,
                                            int tid, int lane, int wid) {
    uint32_t p = cnt;
    #pragma unroll
    for (int d = 1; d < 64; d <<= 1) {
        uint32_t y = __shfl_up(p, (unsigned)d, 64);
        if (lane >= d) p += y;
    }
    if (lane == 63) wsum[wid] = p;
    __syncthreads();
    uint32_t off = 0;
    #pragma unroll
    for (int w = 0; w < 4; ++w) if (w < wid) off += wsum[w];
    p += off;
    uint32_t target = S - kcur + 1u;
    if (p >= target && (p - cnt) < target) {
        bc[0] = (uint32_t)tid;
        bc[1] = kcur - (S - p);
        bc[2] = cnt;
    }
    __syncthreads();
    SelOut o; o.bin = bc[0]; o.k = bc[1]; o.cnt = bc[2];
    return o;
}

// Wave-local 256-bin select: lane L owns bins 4L..4L+3 (ascending). No block
// barriers — one 6-shfl scan + ballot locate + 3-shfl broadcast.
__device__ __forceinline__ void wave_select(const uint32_t c[4], uint32_t S, uint32_t kcur,
                                            int lane, uint32_t& bin, uint32_t& kloc,
                                            uint32_t& cnt) {
    uint32_t t = c[0] + c[1] + c[2] + c[3];
    uint32_t p = t;
    #pragma unroll
    for (int d = 1; d < 64; d <<= 1) {
        uint32_t y = __shfl_up(p, (unsigned)d, 64);
        if (lane >= d) p += y;
    }
    uint32_t excl = p - t;
    uint32_t target = S - kcur + 1u;       // ascending-prefix crossing
    bool cross = (p >= target) && (excl < target);   // exactly one lane
    unsigned long long bal = __ballot(cross);
    uint32_t lbin = 0, lk = 0, lcn = 0;
    if (cross) {
        uint32_t cum = excl;
        #pragma unroll
        for (int i = 0; i < 4; ++i) {
            uint32_t nc = cum + c[i];
            if (cum < target && nc >= target) {       // first crossing sub-bin
                lbin = 4u * (uint32_t)lane + (uint32_t)i;
                lk   = kcur - (S - nc);               // rank within bin
                lcn  = c[i];
            }
            cum = nc;
        }
    }
    int src = __ffsll(bal) - 1;
    bin  = (uint32_t)__shfl((int)lbin, src, 64);
    kloc = (uint32_t)__shfl((int)lk,  src, 64);
    cnt  = (uint32_t)__shfl((int)lcn, src, 64);
}

extern "C" __global__ void __launch_bounds__(NT, 4)
topk_mask_kernel(const float* __restrict__ x, const float* __restrict__ w,
                 float* __restrict__ out) {
    __shared__ uint32_t hist8[NH][HPAD];    // 8448 B, round-1 only
    __shared__ uint32_t hist2[2][HXS];      // per-wave skewed hists (fast path)
    __shared__ uint32_t wsum[4];            // fallback select
    __shared__ uint32_t bc[3];              // fallback select
    __shared__ uint32_t eqidx[2][MAXEQ];    // threshold-equal indices per tail
    __shared__ uint32_t s_ec, s_cutw;       // fallback ties
    __shared__ uint32_t listKey[2][CAP];    // compacted candidates (transformed)
    __shared__ uint16_t listIdx[2][CAP];
    __shared__ uint32_t listCnt[2];
    __shared__ uint32_t r1res[2][3];        // round-1 (bin, k, cnt) per tail
    __shared__ uint32_t fres[2][2];         // final (prefix, cut) per tail

    const int tid  = threadIdx.x;
    const int lane = tid & 63;
    const int wid  = tid >> 6;
    const int hcopy = (wid << 1) | (lane & 1);
    const size_t row = blockIdx.x;

    const float4* xr = (const float4*)(x + row * (size_t)ROWLEN);
    const float4* wr = (const float4*)w;

    // ---- load row (coalesced 16B/lane), form products, keep KEYS in regs ----
    uint32_t key[VPT][4];
    #pragma unroll
    for (int j = 0; j < VPT; ++j) {
        float4 a = xr[j * NT + tid];
        float4 b = wr[j * NT + tid];
        key[j][0] = f2key(a.x * b.x);
        key[j][1] = f2key(a.y * b.y);
        key[j][2] = f2key(a.z * b.z);
        key[j][3] = f2key(a.w * b.w);
    }

    for (int i = tid; i < NH * HPAD; i += NT) ((uint32_t*)hist8)[i] = 0;
    if (tid < 2) listCnt[tid] = 0;
    __syncthreads();                                          // B1

    // ---- round-1 histogram over top byte (8 skewed copies, all waves) ----
    #pragma unroll
    for (int j = 0; j < VPT; ++j)
        #pragma unroll
        for (int c = 0; c < 4; ++c)
            atomicAdd(&hist8[hcopy][key[j][c] >> 24], 1u);
    __syncthreads();                                          // B2

    // ---- round-1 select: wave 0 = top tail, wave 1 = bottom tail ----
    // Transformed top byte of ~key is 255 - top byte of key.
    if (wid < 2) {
        uint32_t c[4];
        #pragma unroll
        for (int i = 0; i < 4; ++i) {
            uint32_t b  = 4u * (uint32_t)lane + (uint32_t)i;  // transformed bin
            uint32_t rb = wid ? (255u - b) : b;               // raw byte
            uint32_t s = 0;
            #pragma unroll
            for (int h = 0; h < NH; ++h) s += hist8[h][rb];
            c[i] = s;
        }
        uint32_t bin, kloc, cnt;
        wave_select(c, ROWLEN, KSEL, lane, bin, kloc, cnt);
        if (lane == 0) { r1res[wid][0] = bin; r1res[wid][1] = kloc; r1res[wid][2] = cnt; }
    }
    __syncthreads();                                          // B3

    const uint32_t bin0 = r1res[0][0], k0 = r1res[0][1], S0 = r1res[0][2];
    const uint32_t bin1 = r1res[1][0], k1 = r1res[1][1], S1 = r1res[1][2];
    uint32_t Thi, Tlo; int cutHi, cutLo;

    if (S0 > CAP || S1 > CAP) {
        // ---- block-wide exact fallback (block-uniform; practically never) ----
        uint32_t Tk[2]; int cv[2];
        for (int pass = 0; pass < 2; ++pass) {
            uint32_t prefix = (pass ? bin1 : bin0) << 24;
            uint32_t kcur = pass ? k1 : k0, S = pass ? S1 : S0;
            for (int shift = 16; shift >= 0; shift -= 8) {
                hist2[0][tid] = 0;
                __syncthreads();
                #pragma unroll
                for (int j = 0; j < VPT; ++j)
                    #pragma unroll
                    for (int c = 0; c < 4; ++c) {
                        uint32_t tk = pass ? ~key[j][c] : key[j][c];
                        if (((tk ^ prefix) >> (shift + 8)) == 0u)
                            atomicAdd(&hist2[0][(tk >> shift) & 0xFFu], 1u);
                    }
                __syncthreads();
                SelOut s = select256(hist2[0][tid], S, kcur, wsum, bc, tid, lane, wid);
                prefix |= s.bin << shift; kcur = s.k; S = s.cnt;
            }
            if (tid == 0) { s_ec = 0; s_cutw = 0x7FFFFFFFu; }
            __syncthreads();
            #pragma unroll
            for (int j = 0; j < VPT; ++j)
                #pragma unroll
                for (int c = 0; c < 4; ++c) {
                    uint32_t tk = pass ? ~key[j][c] : key[j][c];
                    if (tk == prefix) {
                        uint32_t pos = atomicAdd(&s_ec, 1u);
                        if (pos < MAXEQ) eqidx[0][pos] = (uint32_t)((j * NT + tid) * 4 + c);
                    }
                }
            __syncthreads();
            uint32_t ec = s_ec; int cut;
            if (ec <= MAXEQ) {
                if ((uint32_t)tid < ec) {
                    uint32_t my = eqidx[0][tid], rank = 0;
                    for (uint32_t j2 = 0; j2 < ec; ++j2)
                        rank += (eqidx[0][j2] < my) ? 1u : 0u;
                    if (rank + 1u == kcur) s_cutw = my;       // unique writer
                }
                __syncthreads();
                cut = (int)s_cutw;
            } else cut = 0x7FFFFFFF;
            Tk[pass] = prefix; cv[pass] = cut;
            __syncthreads();
        }
        Thi = Tk[0]; Tlo = Tk[1]; cutHi = cv[0]; cutLo = cv[1];
    } else {
        // ---- compaction: plain atomics (measured cheapest in R1), one scan ----
        const uint32_t bRawHi = bin0, bRawLo = 255u - bin1;
        #pragma unroll
        for (int j = 0; j < VPT; ++j)
            #pragma unroll
            for (int c = 0; c < 4; ++c) {
                uint32_t kk = key[j][c];
                uint32_t b = kk >> 24;
                uint32_t idx = (uint32_t)((j * NT + tid) * 4 + c);
                if (b == bRawHi) {
                    uint32_t pos = atomicAdd(&listCnt[0], 1u);
                    listKey[0][pos] = kk;                 // exactly S0 <= CAP match
                    listIdx[0][pos] = (uint16_t)idx;
                }
                if (b == bRawLo) {
                    uint32_t pos = atomicAdd(&listCnt[1], 1u);
                    listKey[1][pos] = ~kk;                // store transformed key
                    listIdx[1][pos] = (uint16_t)idx;
                }
            }
        __syncthreads();                                      // B4

        // ---- wave-specialized refinement: ZERO block barriers inside ----
        if (wid < 2) {
            const int p = wid;
            const uint32_t lc = listCnt[p];
            uint32_t* h = hist2[p];
            const uint32_t* lk = listKey[p];
            const uint16_t* li = listIdx[p];
            uint32_t prefix = (p ? bin1 : bin0) << 24;
            uint32_t kcur = p ? k1 : k0, S = p ? S1 : S0;

            for (int shift = 16; shift >= 0; shift -= 8) {
                #pragma unroll
                for (int i = 0; i < 4; ++i) h[HX(4u * (uint32_t)lane + i)] = 0;
                __builtin_amdgcn_wave_barrier();       // wave-local LDS ordering
                for (uint32_t i = (uint32_t)lane; i < lc; i += 64) {
                    uint32_t tk = lk[i];
                    if (((tk ^ prefix) >> (shift + 8)) == 0u)
                        atomicAdd(&h[HX((tk >> shift) & 0xFFu)], 1u);
                }
                __builtin_amdgcn_wave_barrier();
                uint32_t c[4];
                #pragma unroll
                for (int i = 0; i < 4; ++i) c[i] = h[HX(4u * (uint32_t)lane + i)];
                uint32_t bin, kloc, cnt;
                wave_select(c, S, kcur, lane, bin, kloc, cnt);
                prefix |= bin << shift; kcur = kloc; S = cnt;
            }

            // ---- wave-local tie resolution (ec == S in this path) ----
            uint32_t* eq = eqidx[p];
            uint32_t ec = 0;
            for (uint32_t base = 0; base < lc; base += 64) {
                uint32_t i = base + (uint32_t)lane;
                bool m = (i < lc) && (lk[i] == prefix);
                unsigned long long bal = __ballot(m);
                if (m) {
                    uint32_t pos = ec + (uint32_t)__popcll(bal & ((1ull << lane) - 1ull));
                    if (pos < MAXEQ) eq[pos] = li[i];
                }
                ec += (uint32_t)__popcll(bal);
            }
            __builtin_amdgcn_wave_barrier();
            int cut = 0x7FFFFFFF;
            if (ec <= MAXEQ) {
                uint32_t fcut = 0xFFFFFFFFu;
                for (uint32_t i = (uint32_t)lane; i < ec; i += 64) {
                    uint32_t my = eq[i], rank = 0;
                    for (uint32_t j2 = 0; j2 < ec; ++j2)
                        rank += (eq[j2] < my) ? 1u : 0u;
                    if (rank + 1u == kcur) fcut = my;          // unique lane+entry
                }
                unsigned long long bal = __ballot(fcut != 0xFFFFFFFFu);
                if (bal) {
                    int src = __ffsll(bal) - 1;
                    cut = __shfl((int)fcut, src, 64);
                }
            }
            if (lane == 0) { fres[p][0] = prefix; fres[p][1] = (uint32_t)cut; }
        }
        __syncthreads();                                      // B5
        Thi = fres[0][0]; cutHi = (int)fres[0][1];
        Tlo = fres[1][0]; cutLo = (int)fres[1][1];
    }

    // ---- masked output (coalesced 16B/lane regular stores) ----
    float4* orow = (float4*)(out + row * (size_t)ROWLEN);
    #pragma unroll
    for (int j = 0; j < VPT; ++j) {
        float f[4];
        #pragma unroll
        for (int c = 0; c < 4; ++c) {
            uint32_t kh = key[j][c];
            uint32_t kl = ~kh;
            int idx = (j * NT + tid) * 4 + c;
            bool z = (kh > Thi) || (kh == Thi && idx <= cutHi) ||
                     (kl > Tlo) || (kl == Tlo && idx <= cutLo);
            f[c] = z ? 0.0f : key2f(kh);
        }
        orow[j * NT + tid] = make_float4(f[0], f[1], f[2], f[3]);
    }
}

extern "C" void kernel_launch(void* const* d_in, const int* in_sizes, int n_in,
                              void* d_out, int out_size, void* d_ws, size_t ws_size,
                              hipStream_t stream) {
    const float* x = (const float*)d_in[0];
    const float* w = (const float*)d_in[1];
    // d_in[2] is k (scalar int) == 64, baked in as KSEL
    float* out = (float*)d_out;
    const int rows = out_size / ROWLEN;   // 8192
    topk_mask_kernel<<<dim3(rows), dim3(NT), 0, stream>>>(x, w, out);
}